// Round 7
// baseline (259.704 us; speedup 1.0000x reference)
//
#include <hip/hip_runtime.h>
#include <hip/hip_fp16.h>
#include <math.h>

// FBP adjoint as dense f16 MFMA GEMM with ON-THE-FLY sparse A.
//   out[b,i0,i1,i2] = (1/A) * sum_{j,k} W[(i0,i2),(j,k)] * x[b,j,i1,k]
// C[M=1089, N=4224(i1*128+b)] = W[MxK] . Xt[NxK]^T, K=3993 padded to 4032.
// R16: non-gemm is invariant ~107us across 5 prep structures -> model:
// ~40us fixed overhead + prep ~65-70 + gemm. gemm FETCH decomposition:
// ~74MB of 77MB is W (9.3MB x 8 XCDs) -- and W is 97% zeros (2 bilinear
// taps per 33-col block). So: DELETE W. gemm synthesizes its 64x64 A-tile
// per K-step in registers from a 121-entry cos/sin LDS table (bit-identical
// fmaf/floorf/__float2half_rn chain) and ds_write_b128's it into the same
// swizzled As layout; B staging via global_load_lds unchanged. Removes W's
// fetch from gemm, W's fill from prep (36% of blocks), halves drained loads
// per step. Prep: R15 transpose + aligned-float4 reads (head/tail shift;
// x rows are only 4B-aligned) + uint4 writes.

#define PDIM 33
#define PP   1089
#define A_   121
#define K_   3993
#define KP   4032
#define MT2  18              // M tiles (64)
#define NT2  66              // N tiles (64) = 33 i1 * 2 b-halves
#define NWG  1188            // MT2*NT2
#define OUTB 35937           // 33*33*33
#define XTB  2048            // 128 b * 16 j-groups

typedef _Float16 f16x8 __attribute__((ext_vector_type(8)));
typedef float    f32x4 __attribute__((ext_vector_type(4)));
typedef _Float16 h2v   __attribute__((ext_vector_type(2)));

typedef __attribute__((address_space(1))) const unsigned int* gp_t;
typedef __attribute__((address_space(3))) unsigned int*       lp_t;

static __device__ __forceinline__ unsigned short cvt1_rtz(float v)
{
    return (unsigned short)__builtin_bit_cast(unsigned int,
               __builtin_amdgcn_cvt_pkrtz(v, v));
}

// ---------------- prep: Xt transpose-pack (W is gone) ----------------

__global__ __launch_bounds__(256)
void prep_kernel(const float* __restrict__ x, __half* __restrict__ Xt)
{
    __shared__ unsigned short lh[8752];      // 8 j-rows [33 i1][33 k] (+pad)
    const int blk = blockIdx.x;
    const int t   = threadIdx.x;
    const int b   = blk >> 4;
    const int g   = blk & 15;

    const float* src = x + (size_t)b * (A_ * PP)
                         + (size_t)(g < 15 ? g * 8712 : 120 * PP);
    const int nTot = (g < 15) ? 8712 : PP;

    // aligned-float4 read with head/tail shift (src is only 4B-aligned)
    {
        const int sh = ((16 - (int)((size_t)src & 15)) >> 2) & 3;
        if (t < sh) lh[t] = cvt1_rtz(src[t]);
        const int nv = (nTot - sh) >> 2;
        const float4* s4 = (const float4*)(src + sh);
        for (int e = t; e < nv; e += 256) {
            float4 v = s4[e];
            int o = sh + 4 * e;
            lh[o + 0] = cvt1_rtz(v.x);
            lh[o + 1] = cvt1_rtz(v.y);
            lh[o + 2] = cvt1_rtz(v.z);
            lh[o + 3] = cvt1_rtz(v.w);
        }
        const int tb  = sh + 4 * nv;
        const int rem = nTot - tb;
        if (t < rem) lh[tb + t] = cvt1_rtz(src[tb + t]);
    }
    __syncthreads();

    if (g < 15) {
        // 33 i1-rows x 33 uint4 (264 halves) at kk = g*264, 16B-aligned.
#define LH8(c) (unsigned int)(((c) < rem8) ? lh[j0p * PP + ib + k0p + (c)] \
                                           : lh[(j0p + 1) * PP + ib + ((c) - rem8)])
        for (int e = t; e < 33 * 33; e += 256) {
            int i1 = e / 33, q = e - i1 * 33;
            int le = 8 * q;
            int j0p = le / 33;
            int k0p = le - j0p * 33;
            int rem8 = 33 - k0p;
            int ib = i1 * PDIM;
            unsigned int d0 = LH8(0) | (LH8(1) << 16);
            unsigned int d1 = LH8(2) | (LH8(3) << 16);
            unsigned int d2 = LH8(4) | (LH8(5) << 16);
            unsigned int d3 = LH8(6) | (LH8(7) << 16);
            uint4* drow = (uint4*)(Xt + (size_t)(i1 * 128 + b) * KP + g * 264);
            drow[q] = make_uint4(d0, d1, d2, d3);
        }
#undef LH8
    } else {
        // j=120 (33 halves) + zero pad to kk in [3960,4032): 9 uint4/row.
#define LHT(c) (unsigned int)((le + (c) < PDIM) ? lh[ib + le + (c)] : 0u)
        for (int e = t; e < 33 * 9; e += 256) {
            int i1 = e / 9, q = e - i1 * 9;
            int le = 8 * q;
            int ib = i1 * PDIM;
            unsigned int d0 = LHT(0) | (LHT(1) << 16);
            unsigned int d1 = LHT(2) | (LHT(3) << 16);
            unsigned int d2 = LHT(4) | (LHT(5) << 16);
            unsigned int d3 = LHT(6) | (LHT(7) << 16);
            uint4* drow = (uint4*)(Xt + (size_t)(i1 * 128 + b) * KP + 3960);
            drow[q] = make_uint4(d0, d1, d2, d3);
        }
#undef LHT
    }
}

// GEMM: C = W(on-the-fly) . Xt^T, 64x64 tile, BK=64, 4 waves, 32x32/wave.
// R13 XCD-chunked mapping + R9 2-barrier loop; A synthesized per step.
__global__ __launch_bounds__(256)
void gemm_kernel(const __half* __restrict__ Xt, const float* __restrict__ angles,
                 float* __restrict__ out, float invA)
{
    __shared__ _Float16 As[64 * 64];     // 8 KB, chunk-swizzled (written here)
    __shared__ _Float16 Bs[64 * 64];     // 8 KB, global_load_lds
    __shared__ float2   csl[A_];

    // ---- XCD-aware bijective remap (blk%8 = XCD; nwg=1188: q=148,r=4) ----
    const int b0  = blockIdx.x;
    const int xcd = b0 & 7;
    const int pos = b0 >> 3;
    const int dd0 = (xcd < 4) ? xcd * 149 + pos
                              : 596 + (xcd - 4) * 148 + pos;
    int tileM, tileN;
    if (dd0 < 324) {                     // chunks 0,1: 9 panels each
        int c = dd0 / 162, l = dd0 - c * 162;
        tileM = l / 9;
        tileN = c * 9 + (l - tileM * 9);
    } else {                             // chunks 2..7: 8 panels each
        int dd = dd0 - 324;
        int c = dd / 144, l = dd - c * 144;
        tileM = l >> 3;
        tileN = 18 + c * 8 + (l & 7);
    }

    const int t     = threadIdx.x;
    const int lane  = t & 63;
    const int wave  = t >> 6;
    const int warpM = wave >> 1;
    const int warpN = wave & 1;
    const int quad  = lane >> 4;
    const int l15   = lane & 15;

    if (t < A_) {
        float s, c;
        sincosf(angles[t], &s, &c);
        csl[t] = make_float2(c, s);
    }

    f32x4 acc[2][2] = {};

    const __half* Bb = Xt + (size_t)(tileN * 64) * KP;

    // B staging: chunk cidx (0..511) = 16B = (row=cidx>>3, seg=cidx&7).
    // Global k-seg fetched = seg ^ (row&7); LDS dest linear.
    int srow[2], ssego[2];
#pragma unroll
    for (int i = 0; i < 2; ++i) {
        int cidx = t + i * 256;
        int row  = cidx >> 3;
        int seg  = cidx & 7;
        srow[i]  = row;
        ssego[i] = (seg ^ (row & 7)) * 8;
    }

    // ---- A synthesis constants: thread = (row r, col-quarter q16) ----
    const int r   = t & 63;
    const int q16 = t >> 6;              // 16-col quarter, global segs 2q,2q+1
    const int m   = tileM * 64 + r;
    const bool mv = (m < PP);
    const int i0m = m / PDIM;
    const int i2m = m - i0m * PDIM;
    const float u0 = (float)(i0m - 16);
    const float u2 = (float)(i2m - 16);
    unsigned int* As32 = (unsigned int*)As;
    const int wa0 = r * 32 + (((2 * q16)     ^ (r & 7)) * 4);  // dwords
    const int wa1 = r * 32 + (((2 * q16 + 1) ^ (r & 7)) * 4);

    // Frag-read rows: row rr, k-seg ks -> rr*64 + (ks^(rr&7))*8
    int arow[2], brow[2];
#pragma unroll
    for (int s = 0; s < 2; ++s) {
        arow[s] = warpM * 32 + s * 16 + l15;
        brow[s] = warpN * 32 + s * 16 + l15;
    }

    for (int kb = 0; kb < KP; kb += 64) {
        __syncthreads();
        // ---- issue B loads (async, direct to LDS) ----
#pragma unroll
        for (int i = 0; i < 2; ++i) {
            const __half* gb = Bb + (size_t)srow[i] * KP + kb + ssego[i];
            __builtin_amdgcn_global_load_lds((gp_t)(const void*)gb,
                (lp_t)(void*)&Bs[(t + i * 256) * 8], 16, 0, 0);
        }
        // ---- synthesize A halves for cols [kb+q16*16, +16) (in shadow) ----
        {
            const int kkb  = kb + q16 * 16;
            const int ja   = kkb / PDIM;
            const int jb   = ja + 1;
            const int jb33 = jb * PDIM;
            const int ka   = kkb - ja * PDIM;
            int k0a = -100, k0b = -100;
            unsigned int w0ah = 0, w1ah = 0, w0bh = 0, w1bh = 0;
            if (mv && ja < A_) {
                float2 cs = csl[ja];
                float ix = fmaf(u2, cs.x, fmaf(u0, cs.y, 16.0f));
                float fl = floorf(ix);
                k0a = (int)fl;
                float w1 = ix - fl;
                w0ah = (unsigned int)__builtin_bit_cast(unsigned short,
                           __float2half_rn(1.0f - w1));
                w1ah = (unsigned int)__builtin_bit_cast(unsigned short,
                           __float2half_rn(w1));
            }
            if (mv && jb < A_) {
                float2 cs = csl[jb];
                float ix = fmaf(u2, cs.x, fmaf(u0, cs.y, 16.0f));
                float fl = floorf(ix);
                k0b = (int)fl;
                float w1 = ix - fl;
                w0bh = (unsigned int)__builtin_bit_cast(unsigned short,
                           __float2half_rn(1.0f - w1));
                w1bh = (unsigned int)__builtin_bit_cast(unsigned short,
                           __float2half_rn(w1));
            }
#define HS(k, k0v, w0v, w1v) \
    ((k) == (k0v) ? (w0v) : ((k) == (k0v) + 1 ? (w1v) : 0u))
#define HV(kc) ((kkb + (kc)) < jb33 ? HS(ka + (kc), k0a, w0ah, w1ah) \
                                    : HS((kkb + (kc)) - jb33, k0b, w0bh, w1bh))
            unsigned int d0 = HV(0)  | (HV(1)  << 16);
            unsigned int d1 = HV(2)  | (HV(3)  << 16);
            unsigned int d2 = HV(4)  | (HV(5)  << 16);
            unsigned int d3 = HV(6)  | (HV(7)  << 16);
            unsigned int d4 = HV(8)  | (HV(9)  << 16);
            unsigned int d5 = HV(10) | (HV(11) << 16);
            unsigned int d6 = HV(12) | (HV(13) << 16);
            unsigned int d7 = HV(14) | (HV(15) << 16);
#undef HV
#undef HS
            *(uint4*)(As32 + wa0) = make_uint4(d0, d1, d2, d3);
            *(uint4*)(As32 + wa1) = make_uint4(d4, d5, d6, d7);
        }
        __syncthreads();

        f16x8 af[2][2], bf[2][2];
#pragma unroll
        for (int h = 0; h < 2; ++h) {
#pragma unroll
            for (int s = 0; s < 2; ++s) {
                int ks = h * 4 + quad;
                af[h][s] = *(const f16x8*)&As[arow[s] * 64 + ((ks ^ (arow[s] & 7)) * 8)];
                bf[h][s] = *(const f16x8*)&Bs[brow[s] * 64 + ((ks ^ (brow[s] & 7)) * 8)];
            }
        }
#pragma unroll
        for (int h = 0; h < 2; ++h)
#pragma unroll
            for (int ms = 0; ms < 2; ++ms)
#pragma unroll
                for (int ns = 0; ns < 2; ++ns)
                    acc[ms][ns] = __builtin_amdgcn_mfma_f32_16x16x32_f16(
                        af[h][ms], bf[h][ns], acc[ms][ns], 0, 0, 0);
    }

    // Epilogue: C row mm=(i0,i2), col nglob=(i1*128+b); out[b,i0,i1,i2].
#pragma unroll
    for (int ns = 0; ns < 2; ++ns) {
        int nglob = tileN * 64 + warpN * 32 + ns * 16 + l15;
        int i1 = nglob >> 7;
        int b  = nglob & 127;
        float* ob = out + (size_t)b * OUTB + (size_t)i1 * PDIM;
#pragma unroll
        for (int ms = 0; ms < 2; ++ms) {
#pragma unroll
            for (int rr = 0; rr < 4; ++rr) {
                int mm = tileM * 64 + warpM * 32 + ms * 16 + quad * 4 + rr;
                if (mm < PP) {
                    int i0 = mm / PDIM;
                    int i2 = mm - i0 * PDIM;
                    ob[(size_t)i0 * PP + i2] = acc[ms][ns][rr] * invA;
                }
            }
        }
    }
}

// ---------------- fallback (R6, proven ~151 us) ----------------

#define ROWW 47
#define PADL 7
#define BLK  384
#define NV   3
#define GRID 1280

#if defined(__has_builtin)
#if __has_builtin(__builtin_amdgcn_fractf)
#define FRACTF(x) __builtin_amdgcn_fractf(x)
#endif
#endif
#ifndef FRACTF
#define FRACTF(x) ((x) - floorf(x))
#endif

__device__ __forceinline__ float fdot2u(unsigned int a, unsigned int b, float c)
{
    return __builtin_amdgcn_fdot2(__builtin_bit_cast(h2v, a),
                                  __builtin_bit_cast(h2v, b), c, false);
}

__global__ __launch_bounds__(BLK)
void fbp_adjoint_kernel(const float* __restrict__ x,
                        const float* __restrict__ angles,
                        float* __restrict__ out,
                        int nslice, float invA)
{
    __shared__ unsigned int dr[A_ * ROWW];
    __shared__ float2       cs_lds[A_];

    const int t = threadIdx.x;
    for (int j = t; j < A_; j += BLK) {
        float s, c;
        sincosf(angles[j], &s, &c);
        cs_lds[j] = make_float2(c, s);
    }

    float u0[NV], u2[NV];
#pragma unroll
    for (int nn = 0; nn < NV; ++nn) {
        int n  = t + nn * BLK;
        int nc = (n < PP) ? n : (PP - 1);
        int q0 = nc / PDIM;
        int q2 = nc - q0 * PDIM;
        u0[nn] = (float)(q0 - 16);
        u2[nn] = (float)(q2 - 16);
    }

    for (int slice = blockIdx.x; slice < nslice; slice += GRID) {
        if (slice != (int)blockIdx.x) __syncthreads();
        const int hb = slice / PDIM;
        const int i1 = slice - hb * PDIM;
        const int b0 = 2 * hb;
        const float* r0 = x + (size_t)b0 * (A_ * PP) + (size_t)i1 * PDIM;
        const float* r1 = r0 + (size_t)(A_ * PP);
        for (int e = t; e < A_ * ROWW; e += BLK) {
            int j = e / ROWW;
            int p = e - j * ROWW;
            int k = p - PADL;
            float f0 = 0.0f, f1 = 0.0f;
            if (k >= 0 && k < PDIM) {
                size_t o = (size_t)j * PP + k;
                f0 = r0[o];
                f1 = r1[o];
            }
            dr[e] = __builtin_bit_cast(unsigned int,
                        __halves2half2(__float2half_rn(f0), __float2half_rn(f1)));
        }
        __syncthreads();

        float a0[NV] = {0.0f, 0.0f, 0.0f};
        float a1[NV] = {0.0f, 0.0f, 0.0f};
#pragma unroll 2
        for (int j = 0; j < A_; ++j) {
            float2 cj = cs_lds[j];
            const unsigned int* base = &dr[j * ROWW];
#pragma unroll
            for (int nn = 0; nn < NV; ++nn) {
                float ixp = fmaf(u2[nn], cj.x, fmaf(u0[nn], cj.y, 23.0f));
                int   kp  = (int)ixp;
                float w1  = FRACTF(ixp);
                unsigned int wp = __builtin_bit_cast(unsigned int,
                                    __builtin_amdgcn_cvt_pkrtz(1.0f - w1, w1));
                unsigned int d0 = base[kp];
                unsigned int d1 = base[kp + 1];
                unsigned int p0 = __builtin_amdgcn_perm(d1, d0, 0x05040100u);
                unsigned int p1 = __builtin_amdgcn_perm(d1, d0, 0x07060302u);
                a0[nn] = fdot2u(p0, wp, a0[nn]);
                a1[nn] = fdot2u(p1, wp, a1[nn]);
            }
        }

        float* ob0 = out + (size_t)b0 * OUTB + (size_t)i1 * PDIM;
        float* ob1 = ob0 + (size_t)OUTB;
#pragma unroll
        for (int nn = 0; nn < NV; ++nn) {
            int n = t + nn * BLK;
            if (n < PP) {
                int q0 = n / PDIM;
                int q2 = n - q0 * PDIM;
                size_t o = (size_t)q0 * PP + q2;
                ob0[o] = a0[nn] * invA;
                ob1[o] = a1[nn] * invA;
            }
        }
    }
}

// ---------------- launch ----------------

extern "C" void kernel_launch(void* const* d_in, const int* in_sizes, int n_in,
                              void* d_out, int out_size, void* d_ws, size_t ws_size,
                              hipStream_t stream)
{
    const float* x      = (const float*)d_in[0];
    const float* angles = (const float*)d_in[1];
    float* out          = (float*)d_out;

    const int A = in_sizes[1];                    // 121
    const int B = in_sizes[0] / (A * PP);         // 128
    const float invA = 1.0f / (float)A;

    const size_t xtBytes = (size_t)(PDIM * B) * KP * sizeof(__half); // 34.1 MB

    if (ws_size >= xtBytes && A == A_ && B == 128) {
        __half* Xt = (__half*)d_ws;
        prep_kernel<<<XTB, 256, 0, stream>>>(x, Xt);
        gemm_kernel<<<NWG, 256, 0, stream>>>(Xt, angles, out, invA);
    } else {
        const int nslice = (B / 2) * PDIM;
        dim3 grid(GRID < nslice ? GRID : nslice);
        fbp_adjoint_kernel<<<grid, BLK, 0, stream>>>(x, angles, out,
                                                     nslice, invA);
    }
}

// Round 8
// 259.265 us; speedup vs baseline: 1.0017x; 1.0017x over previous
//
#include <hip/hip_runtime.h>
#include <hip/hip_fp16.h>
#include <math.h>

// FBP adjoint as dense f16 MFMA GEMM.
//   out[b,i0,i1,i2] = (1/A) * sum_{j,k} W[(i0,i2),(j,k)] * x[b,j,i1,k]
// C[M=1089, N=4224(i1*128+b)] = W[MxK] . Xt[NxK]^T, K=3993 padded to 4032.
// R17: R16's on-the-fly A synthesis was VALU-bound (VALUBusy 76%, MfmaUtil
// 9.7%, gemm 162us) -> reverted; W-based gemm + R13 prep restored verbatim.
// New single change: per-block K-phase rotation (start kb at (d*5)%63, wrap).
// Mechanism: all blocks stepped K in lockstep -> same-panel blocks demanded
// identical W/Xt lines each step (convoyed L2/L3 bursts; explains R11/R12
// regressions and the 2.7TB/s plateau). Rotation decorrelates the address
// schedule at zero structural cost. K-order change is not bit-identical but
// absmax is the f16 quantization floor (fallback matches it too).

#define PDIM 33
#define PP   1089
#define A_   121
#define K_   3993
#define KP   4032
#define MP   1152            // padded M (18*64)
#define MT2  18              // M tiles (64)
#define NT2  66              // N tiles (64) = 33 i1 * 2 b-halves
#define NWG  1188            // MT2*NT2
#define NSTEP 63             // KP/64
#define OUTB 35937           // 33*33*33

typedef _Float16 f16x8 __attribute__((ext_vector_type(8)));
typedef float    f32x4 __attribute__((ext_vector_type(4)));
typedef _Float16 h2v   __attribute__((ext_vector_type(2)));

typedef __attribute__((address_space(1))) const unsigned int* gp_t;
typedef __attribute__((address_space(3))) unsigned int*       lp_t;

// ---------------- fused prep: Xt pack + W fill (R13 exact) ----------------

__global__ __launch_bounds__(256)
void prep_kernel(const float* __restrict__ x, const float* __restrict__ angles,
                 __half* __restrict__ Xt, __half* __restrict__ W)
{
    const int blk = blockIdx.x;
    const int t   = threadIdx.x;

    if (blk < PDIM * 128) {
        // ---- Xt row n=(i1*128+b): x[b,:,i1,:] flattened (j,k) fp16, K-pad 0.
        const int n  = blk;
        const int i1 = n >> 7;
        const int b  = n & 127;
        const float* src = x + (size_t)b * (A_ * PP) + (size_t)i1 * PDIM;
        unsigned int* dst = (unsigned int*)(Xt + (size_t)n * KP);
        for (int e = t; e < KP / 2; e += 256) {
            int kk0 = 2 * e, kk1 = 2 * e + 1;
            float v0 = 0.0f, v1 = 0.0f;
            if (kk0 < K_) {
                int j = kk0 / PDIM, k = kk0 - j * PDIM;
                v0 = src[(size_t)j * PP + k];
            }
            if (kk1 < K_) {
                int j = kk1 / PDIM, k = kk1 - j * PDIM;
                v1 = src[(size_t)j * PP + k];
            }
            dst[e] = __builtin_bit_cast(unsigned int,
                         __builtin_amdgcn_cvt_pkrtz(v0, v1));
        }
    } else {
        // ---- W row n: zero-fill (int4) then scatter the 2 bilinear taps/angle.
        const int n = blk - PDIM * 128;      // 0..1151
        __half* row = W + (size_t)n * KP;    // 8064 B, 16B-aligned
        int4 zz = make_int4(0, 0, 0, 0);
        for (int e = t; e < KP / 8; e += 256)
            ((int4*)row)[e] = zz;
        __syncthreads();
        if (n >= PP || t >= A_) return;
        const int j  = t;
        const int i0 = n / PDIM;
        const int i2 = n - i0 * PDIM;
        float s, c;
        sincosf(angles[j], &s, &c);
        float ix = fmaf((float)(i2 - 16), c, fmaf((float)(i0 - 16), s, 16.0f));
        float fl = floorf(ix);
        int   k0 = (int)fl;
        float w1 = ix - fl;
        float w0 = 1.0f - w1;
        __half* seg = row + j * PDIM;
        if (k0 >= 0     && k0 < PDIM)     seg[k0]     = __float2half_rn(w0);
        if (k0 + 1 >= 0 && k0 + 1 < PDIM) seg[k0 + 1] = __float2half_rn(w1);
    }
}

// GEMM: C = W . Xt^T, 64x64 tile, BK=64, 4 waves (2x2), 32x32 per wave.
// R9 2-barrier loop + R13 XCD-chunked mapping + K-phase rotation (R17).
__global__ __launch_bounds__(256)
void gemm_kernel(const __half* __restrict__ W, const __half* __restrict__ Xt,
                 float* __restrict__ out, float invA)
{
    __shared__ _Float16 As[64 * 64];     // 8 KB, chunk-swizzled
    __shared__ _Float16 Bs[64 * 64];     // 8 KB

    // ---- XCD-aware bijective remap (blk%8 = XCD; nwg=1188: q=148,r=4) ----
    const int b0  = blockIdx.x;
    const int xcd = b0 & 7;
    const int pos = b0 >> 3;
    const int d   = (xcd < 4) ? xcd * 149 + pos
                              : 596 + (xcd - 4) * 148 + pos;
    int tileM, tileN;
    if (d < 324) {                       // chunks 0,1: 9 panels each
        int c = d / 162, l = d - c * 162;
        tileM = l / 9;
        tileN = c * 9 + (l - tileM * 9);
    } else {                             // chunks 2..7: 8 panels each
        int dd = d - 324;
        int c = dd / 144, l = dd - c * 144;
        tileM = l >> 3;
        tileN = 18 + c * 8 + (l & 7);
    }

    const int t     = threadIdx.x;
    const int lane  = t & 63;
    const int wave  = t >> 6;
    const int warpM = wave >> 1;
    const int warpN = wave & 1;
    const int quad  = lane >> 4;
    const int l15   = lane & 15;

    f32x4 acc[2][2] = {};

    const __half* Ab = W  + (size_t)(tileM * 64) * KP;
    const __half* Bb = Xt + (size_t)(tileN * 64) * KP;

    // Staging chunk geometry: chunk cidx (0..511) = 16B = (row=cidx>>3,
    // seg=cidx&7). Global k-seg fetched = seg ^ (row&7); LDS dest linear.
    int srow[2], ssego[2];
#pragma unroll
    for (int i = 0; i < 2; ++i) {
        int cidx = t + i * 256;
        int row  = cidx >> 3;
        int seg  = cidx & 7;
        srow[i]  = row;
        ssego[i] = (seg ^ (row & 7)) * 8;   // halves offset within K-slice
    }

    // Frag-read addresses (halves): row r, k-seg ks -> r*64 + (ks^(r&7))*8
    int arow[2], brow[2];
#pragma unroll
    for (int s = 0; s < 2; ++s) {
        arow[s] = warpM * 32 + s * 16 + l15;
        brow[s] = warpN * 32 + s * 16 + l15;
    }

    // ---- K-phase rotation: decorrelate per-block address schedules ----
    int step = (d * 5) % NSTEP;
    for (int i = 0; i < NSTEP; ++i) {
        const int kb = step * 64;
        __syncthreads();
#pragma unroll
        for (int ii = 0; ii < 2; ++ii) {
            const __half* ga = Ab + (size_t)srow[ii] * KP + kb + ssego[ii];
            const __half* gb = Bb + (size_t)srow[ii] * KP + kb + ssego[ii];
            __builtin_amdgcn_global_load_lds((gp_t)(const void*)ga,
                (lp_t)(void*)&As[(t + ii * 256) * 8], 16, 0, 0);
            __builtin_amdgcn_global_load_lds((gp_t)(const void*)gb,
                (lp_t)(void*)&Bs[(t + ii * 256) * 8], 16, 0, 0);
        }
        __syncthreads();

        f16x8 af[2][2], bf[2][2];
#pragma unroll
        for (int h = 0; h < 2; ++h) {
#pragma unroll
            for (int s = 0; s < 2; ++s) {
                int ks = h * 4 + quad;
                af[h][s] = *(const f16x8*)&As[arow[s] * 64 + ((ks ^ (arow[s] & 7)) * 8)];
                bf[h][s] = *(const f16x8*)&Bs[brow[s] * 64 + ((ks ^ (brow[s] & 7)) * 8)];
            }
        }
#pragma unroll
        for (int h = 0; h < 2; ++h)
#pragma unroll
            for (int ms = 0; ms < 2; ++ms)
#pragma unroll
                for (int ns = 0; ns < 2; ++ns)
                    acc[ms][ns] = __builtin_amdgcn_mfma_f32_16x16x32_f16(
                        af[h][ms], bf[h][ns], acc[ms][ns], 0, 0, 0);

        step = (step == NSTEP - 1) ? 0 : step + 1;
    }

    // Epilogue: C row m=(i0,i2), col nglob=(i1*128+b); out[b,i0,i1,i2].
#pragma unroll
    for (int ns = 0; ns < 2; ++ns) {
        int nglob = tileN * 64 + warpN * 32 + ns * 16 + l15;
        int i1 = nglob >> 7;
        int b  = nglob & 127;
        float* ob = out + (size_t)b * OUTB + (size_t)i1 * PDIM;
#pragma unroll
        for (int ms = 0; ms < 2; ++ms) {
#pragma unroll
            for (int r = 0; r < 4; ++r) {
                int m = tileM * 64 + warpM * 32 + ms * 16 + quad * 4 + r;
                if (m < PP) {
                    int i0 = m / PDIM;
                    int i2 = m - i0 * PDIM;
                    ob[(size_t)i0 * PP + i2] = acc[ms][ns][r] * invA;
                }
            }
        }
    }
}

// ---------------- fallback (R6, proven ~151 us) ----------------

#define ROWW 47
#define PADL 7
#define BLK  384
#define NV   3
#define GRID 1280

#if defined(__has_builtin)
#if __has_builtin(__builtin_amdgcn_fractf)
#define FRACTF(x) __builtin_amdgcn_fractf(x)
#endif
#endif
#ifndef FRACTF
#define FRACTF(x) ((x) - floorf(x))
#endif

__device__ __forceinline__ float fdot2u(unsigned int a, unsigned int b, float c)
{
    return __builtin_amdgcn_fdot2(__builtin_bit_cast(h2v, a),
                                  __builtin_bit_cast(h2v, b), c, false);
}

__global__ __launch_bounds__(BLK)
void fbp_adjoint_kernel(const float* __restrict__ x,
                        const float* __restrict__ angles,
                        float* __restrict__ out,
                        int nslice, float invA)
{
    __shared__ unsigned int dr[A_ * ROWW];
    __shared__ float2       cs_lds[A_];

    const int t = threadIdx.x;
    for (int j = t; j < A_; j += BLK) {
        float s, c;
        sincosf(angles[j], &s, &c);
        cs_lds[j] = make_float2(c, s);
    }

    float u0[NV], u2[NV];
#pragma unroll
    for (int nn = 0; nn < NV; ++nn) {
        int n  = t + nn * BLK;
        int nc = (n < PP) ? n : (PP - 1);
        int q0 = nc / PDIM;
        int q2 = nc - q0 * PDIM;
        u0[nn] = (float)(q0 - 16);
        u2[nn] = (float)(q2 - 16);
    }

    for (int slice = blockIdx.x; slice < nslice; slice += GRID) {
        if (slice != (int)blockIdx.x) __syncthreads();
        const int hb = slice / PDIM;
        const int i1 = slice - hb * PDIM;
        const int b0 = 2 * hb;
        const float* r0 = x + (size_t)b0 * (A_ * PP) + (size_t)i1 * PDIM;
        const float* r1 = r0 + (size_t)(A_ * PP);
        for (int e = t; e < A_ * ROWW; e += BLK) {
            int j = e / ROWW;
            int p = e - j * ROWW;
            int k = p - PADL;
            float f0 = 0.0f, f1 = 0.0f;
            if (k >= 0 && k < PDIM) {
                size_t o = (size_t)j * PP + k;
                f0 = r0[o];
                f1 = r1[o];
            }
            dr[e] = __builtin_bit_cast(unsigned int,
                        __halves2half2(__float2half_rn(f0), __float2half_rn(f1)));
        }
        __syncthreads();

        float a0[NV] = {0.0f, 0.0f, 0.0f};
        float a1[NV] = {0.0f, 0.0f, 0.0f};
#pragma unroll 2
        for (int j = 0; j < A_; ++j) {
            float2 cj = cs_lds[j];
            const unsigned int* base = &dr[j * ROWW];
#pragma unroll
            for (int nn = 0; nn < NV; ++nn) {
                float ixp = fmaf(u2[nn], cj.x, fmaf(u0[nn], cj.y, 23.0f));
                int   kp  = (int)ixp;
                float w1  = FRACTF(ixp);
                unsigned int wp = __builtin_bit_cast(unsigned int,
                                    __builtin_amdgcn_cvt_pkrtz(1.0f - w1, w1));
                unsigned int d0 = base[kp];
                unsigned int d1 = base[kp + 1];
                unsigned int p0 = __builtin_amdgcn_perm(d1, d0, 0x05040100u);
                unsigned int p1 = __builtin_amdgcn_perm(d1, d0, 0x07060302u);
                a0[nn] = fdot2u(p0, wp, a0[nn]);
                a1[nn] = fdot2u(p1, wp, a1[nn]);
            }
        }

        float* ob0 = out + (size_t)b0 * OUTB + (size_t)i1 * PDIM;
        float* ob1 = ob0 + (size_t)OUTB;
#pragma unroll
        for (int nn = 0; nn < NV; ++nn) {
            int n = t + nn * BLK;
            if (n < PP) {
                int q0 = n / PDIM;
                int q2 = n - q0 * PDIM;
                size_t o = (size_t)q0 * PP + q2;
                ob0[o] = a0[nn] * invA;
                ob1[o] = a1[nn] * invA;
            }
        }
    }
}

// ---------------- launch ----------------

extern "C" void kernel_launch(void* const* d_in, const int* in_sizes, int n_in,
                              void* d_out, int out_size, void* d_ws, size_t ws_size,
                              hipStream_t stream)
{
    const float* x      = (const float*)d_in[0];
    const float* angles = (const float*)d_in[1];
    float* out          = (float*)d_out;

    const int A = in_sizes[1];                    // 121
    const int B = in_sizes[0] / (A * PP);         // 128
    const float invA = 1.0f / (float)A;

    const size_t wBytes  = (size_t)MP * KP * sizeof(__half);         // 9.29 MB
    const size_t xtBytes = (size_t)(PDIM * B) * KP * sizeof(__half); // 34.1 MB

    if (ws_size >= wBytes + xtBytes && A == A_ && B == 128) {
        __half* W  = (__half*)d_ws;
        __half* Xt = (__half*)((char*)d_ws + wBytes);
        prep_kernel<<<PDIM * B + MP, 256, 0, stream>>>(x, angles, Xt, W);
        gemm_kernel<<<NWG, 256, 0, stream>>>(W, Xt, out, invA);
    } else {
        const int nslice = (B / 2) * PDIM;
        dim3 grid(GRID < nslice ? GRID : nslice);
        fbp_adjoint_kernel<<<grid, BLK, 0, stream>>>(x, angles, out,
                                                     nslice, invA);
    }
}

// Round 9
// 195.158 us; speedup vs baseline: 1.3307x; 1.3285x over previous
//
#include <hip/hip_runtime.h>
#include <hip/hip_fp16.h>
#include <math.h>

// FBP adjoint as dense f16 MFMA GEMM.
//   out[b,i0,i1,i2] = (1/A) * sum_{j,k} W[(i0,i2),(j,k)] * x[b,j,i1,k]
// C[M=1089, N=4224(i1*128+b)] = W[MxK] . Xt[NxK]^T, K=3993 padded to 4032.
// R18: R17's K-rotation REFUTED convoying (FETCH 77->491MB, 6.4x refetch:
// lockstep was constructive L2 sharing) but PROVED fabric does 3.4TB/s ->
// R13's 1.4TB/s was never a BW wall; gemm is exposed-latency-per-step
// (syncthreads drains vmcnt(0) ~600cy vs 80cy MFMA). Fix = 3-buffer ring
// with counted vmcnt (T4/m201 pattern): issue stage(t+2); vmcnt(8) keeps
// t+1,t+2 in flight and only waits for t (issued 2 iters ago = hidden);
// raw s_barrier pair per iter (no vmcnt-0 drain). R10's 1-deep failure:
// waited on same-iter loads (zero overlap) + 5 fences/iter; here depth=2
// and exactly one vmcnt asm + one sched_barrier per iter. LDS 48KB -> 3
// blocks/CU = current effective residency (free). K order sequential ->
// bit-identical absmax.

#define PDIM 33
#define PP   1089
#define A_   121
#define K_   3993
#define KP   4032
#define MP   1152            // padded M (18*64)
#define MT2  18              // M tiles (64)
#define NT2  66              // N tiles (64) = 33 i1 * 2 b-halves
#define NWG  1188            // MT2*NT2
#define NSTEP 63             // KP/64
#define OUTB 35937           // 33*33*33

typedef _Float16 f16x8 __attribute__((ext_vector_type(8)));
typedef float    f32x4 __attribute__((ext_vector_type(4)));
typedef _Float16 h2v   __attribute__((ext_vector_type(2)));

typedef __attribute__((address_space(1))) const unsigned int* gp_t;
typedef __attribute__((address_space(3))) unsigned int*       lp_t;

// ---------------- fused prep: Xt pack + W fill (R13 exact) ----------------

__global__ __launch_bounds__(256)
void prep_kernel(const float* __restrict__ x, const float* __restrict__ angles,
                 __half* __restrict__ Xt, __half* __restrict__ W)
{
    const int blk = blockIdx.x;
    const int t   = threadIdx.x;

    if (blk < PDIM * 128) {
        // ---- Xt row n=(i1*128+b): x[b,:,i1,:] flattened (j,k) fp16, K-pad 0.
        const int n  = blk;
        const int i1 = n >> 7;
        const int b  = n & 127;
        const float* src = x + (size_t)b * (A_ * PP) + (size_t)i1 * PDIM;
        unsigned int* dst = (unsigned int*)(Xt + (size_t)n * KP);
        for (int e = t; e < KP / 2; e += 256) {
            int kk0 = 2 * e, kk1 = 2 * e + 1;
            float v0 = 0.0f, v1 = 0.0f;
            if (kk0 < K_) {
                int j = kk0 / PDIM, k = kk0 - j * PDIM;
                v0 = src[(size_t)j * PP + k];
            }
            if (kk1 < K_) {
                int j = kk1 / PDIM, k = kk1 - j * PDIM;
                v1 = src[(size_t)j * PP + k];
            }
            dst[e] = __builtin_bit_cast(unsigned int,
                         __builtin_amdgcn_cvt_pkrtz(v0, v1));
        }
    } else {
        // ---- W row n: zero-fill (int4) then scatter the 2 bilinear taps/angle.
        const int n = blk - PDIM * 128;      // 0..1151
        __half* row = W + (size_t)n * KP;    // 8064 B, 16B-aligned
        int4 zz = make_int4(0, 0, 0, 0);
        for (int e = t; e < KP / 8; e += 256)
            ((int4*)row)[e] = zz;
        __syncthreads();
        if (n >= PP || t >= A_) return;
        const int j  = t;
        const int i0 = n / PDIM;
        const int i2 = n - i0 * PDIM;
        float s, c;
        sincosf(angles[j], &s, &c);
        float ix = fmaf((float)(i2 - 16), c, fmaf((float)(i0 - 16), s, 16.0f));
        float fl = floorf(ix);
        int   k0 = (int)fl;
        float w1 = ix - fl;
        float w0 = 1.0f - w1;
        __half* seg = row + j * PDIM;
        if (k0 >= 0     && k0 < PDIM)     seg[k0]     = __float2half_rn(w0);
        if (k0 + 1 >= 0 && k0 + 1 < PDIM) seg[k0 + 1] = __float2half_rn(w1);
    }
}

// GEMM: C = W . Xt^T, 64x64 tile, BK=64, 4 waves (2x2), 32x32 per wave.
// R13 XCD-chunked mapping + 3-buffer ring / counted-vmcnt pipeline (R18).
__global__ __launch_bounds__(256)
void gemm_kernel(const __half* __restrict__ W, const __half* __restrict__ Xt,
                 float* __restrict__ out, float invA)
{
    __shared__ _Float16 As[3][64 * 64];  // 3 x 8 KB, chunk-swizzled
    __shared__ _Float16 Bs[3][64 * 64];  // 3 x 8 KB

    // ---- XCD-aware bijective remap (blk%8 = XCD; nwg=1188: q=148,r=4) ----
    const int b0  = blockIdx.x;
    const int xcd = b0 & 7;
    const int pos = b0 >> 3;
    const int d   = (xcd < 4) ? xcd * 149 + pos
                              : 596 + (xcd - 4) * 148 + pos;
    int tileM, tileN;
    if (d < 324) {                       // chunks 0,1: 9 panels each
        int c = d / 162, l = d - c * 162;
        tileM = l / 9;
        tileN = c * 9 + (l - tileM * 9);
    } else {                             // chunks 2..7: 8 panels each
        int dd = d - 324;
        int c = dd / 144, l = dd - c * 144;
        tileM = l >> 3;
        tileN = 18 + c * 8 + (l & 7);
    }

    const int t     = threadIdx.x;
    const int lane  = t & 63;
    const int wave  = t >> 6;
    const int warpM = wave >> 1;
    const int warpN = wave & 1;
    const int quad  = lane >> 4;
    const int l15   = lane & 15;

    f32x4 acc[2][2] = {};

    const __half* Ab = W  + (size_t)(tileM * 64) * KP;
    const __half* Bb = Xt + (size_t)(tileN * 64) * KP;

    // Staging chunk geometry: chunk cidx (0..511) = 16B = (row=cidx>>3,
    // seg=cidx&7). Global k-seg fetched = seg ^ (row&7); LDS dest linear.
    int srow[2], ssego[2];
#pragma unroll
    for (int i = 0; i < 2; ++i) {
        int cidx = t + i * 256;
        int row  = cidx >> 3;
        int seg  = cidx & 7;
        srow[i]  = row;
        ssego[i] = (seg ^ (row & 7)) * 8;   // halves offset within K-slice
    }

    // Frag-read addresses (halves): row r, k-seg ks -> r*64 + (ks^(r&7))*8
    int arow[2], brow[2];
#pragma unroll
    for (int s = 0; s < 2; ++s) {
        arow[s] = warpM * 32 + s * 16 + l15;
        brow[s] = warpN * 32 + s * 16 + l15;
    }

    // 4 global_load_lds per thread per stage.
    auto stage = [&](int sel, int step) {
        const int kb = step * 64;
#pragma unroll
        for (int ii = 0; ii < 2; ++ii) {
            const __half* ga = Ab + (size_t)srow[ii] * KP + kb + ssego[ii];
            const __half* gb = Bb + (size_t)srow[ii] * KP + kb + ssego[ii];
            __builtin_amdgcn_global_load_lds((gp_t)(const void*)ga,
                (lp_t)(void*)&As[sel][(t + ii * 256) * 8], 16, 0, 0);
            __builtin_amdgcn_global_load_lds((gp_t)(const void*)gb,
                (lp_t)(void*)&Bs[sel][(t + ii * 256) * 8], 16, 0, 0);
        }
    };

    auto compute = [&](int sel) {
        f16x8 af[2][2], bf[2][2];
#pragma unroll
        for (int h = 0; h < 2; ++h) {
#pragma unroll
            for (int s = 0; s < 2; ++s) {
                int ks = h * 4 + quad;
                af[h][s] = *(const f16x8*)
                    &As[sel][arow[s] * 64 + ((ks ^ (arow[s] & 7)) * 8)];
                bf[h][s] = *(const f16x8*)
                    &Bs[sel][brow[s] * 64 + ((ks ^ (brow[s] & 7)) * 8)];
            }
        }
#pragma unroll
        for (int h = 0; h < 2; ++h)
#pragma unroll
            for (int ms = 0; ms < 2; ++ms)
#pragma unroll
                for (int ns = 0; ns < 2; ++ns)
                    acc[ms][ns] = __builtin_amdgcn_mfma_f32_16x16x32_f16(
                        af[h][ms], bf[h][ns], acc[ms][ns], 0, 0, 0);
    };

    // ---- prologue: 2 tiles in flight ----
    stage(0, 0);
    stage(1, 1);

    // ---- main loop: i = 0 .. NSTEP-3 ----
    int cur = 0, nx2 = 2;
    for (int i = 0; i < NSTEP - 2; ++i) {
        __builtin_amdgcn_s_barrier();            // all done reading buf[nx2]
        stage(nx2, i + 2);
        asm volatile("s_waitcnt vmcnt(8)" ::: "memory");  // tile i landed
        __builtin_amdgcn_s_barrier();            // whole tile i visible
        __builtin_amdgcn_sched_barrier(0);
        compute(cur);
        cur = (cur == 2) ? 0 : cur + 1;
        nx2 = (nx2 == 2) ? 0 : nx2 + 1;
    }
    // ---- epilogue: tiles NSTEP-2, NSTEP-1 ----
    __builtin_amdgcn_s_barrier();
    asm volatile("s_waitcnt vmcnt(4)" ::: "memory");
    __builtin_amdgcn_s_barrier();
    __builtin_amdgcn_sched_barrier(0);
    compute(cur);
    cur = (cur == 2) ? 0 : cur + 1;
    __builtin_amdgcn_s_barrier();
    asm volatile("s_waitcnt vmcnt(0)" ::: "memory");
    __builtin_amdgcn_s_barrier();
    __builtin_amdgcn_sched_barrier(0);
    compute(cur);

    // Epilogue: C row m=(i0,i2), col nglob=(i1*128+b); out[b,i0,i1,i2].
#pragma unroll
    for (int ns = 0; ns < 2; ++ns) {
        int nglob = tileN * 64 + warpN * 32 + ns * 16 + l15;
        int i1 = nglob >> 7;
        int b  = nglob & 127;
        float* ob = out + (size_t)b * OUTB + (size_t)i1 * PDIM;
#pragma unroll
        for (int ms = 0; ms < 2; ++ms) {
#pragma unroll
            for (int r = 0; r < 4; ++r) {
                int m = tileM * 64 + warpM * 32 + ms * 16 + quad * 4 + r;
                if (m < PP) {
                    int i0 = m / PDIM;
                    int i2 = m - i0 * PDIM;
                    ob[(size_t)i0 * PP + i2] = acc[ms][ns][r] * invA;
                }
            }
        }
    }
}

// ---------------- fallback (R6, proven ~151 us) ----------------

#define ROWW 47
#define PADL 7
#define BLK  384
#define NV   3
#define GRID 1280

#if defined(__has_builtin)
#if __has_builtin(__builtin_amdgcn_fractf)
#define FRACTF(x) __builtin_amdgcn_fractf(x)
#endif
#endif
#ifndef FRACTF
#define FRACTF(x) ((x) - floorf(x))
#endif

__device__ __forceinline__ float fdot2u(unsigned int a, unsigned int b, float c)
{
    return __builtin_amdgcn_fdot2(__builtin_bit_cast(h2v, a),
                                  __builtin_bit_cast(h2v, b), c, false);
}

__global__ __launch_bounds__(BLK)
void fbp_adjoint_kernel(const float* __restrict__ x,
                        const float* __restrict__ angles,
                        float* __restrict__ out,
                        int nslice, float invA)
{
    __shared__ unsigned int dr[A_ * ROWW];
    __shared__ float2       cs_lds[A_];

    const int t = threadIdx.x;
    for (int j = t; j < A_; j += BLK) {
        float s, c;
        sincosf(angles[j], &s, &c);
        cs_lds[j] = make_float2(c, s);
    }

    float u0[NV], u2[NV];
#pragma unroll
    for (int nn = 0; nn < NV; ++nn) {
        int n  = t + nn * BLK;
        int nc = (n < PP) ? n : (PP - 1);
        int q0 = nc / PDIM;
        int q2 = nc - q0 * PDIM;
        u0[nn] = (float)(q0 - 16);
        u2[nn] = (float)(q2 - 16);
    }

    for (int slice = blockIdx.x; slice < nslice; slice += GRID) {
        if (slice != (int)blockIdx.x) __syncthreads();
        const int hb = slice / PDIM;
        const int i1 = slice - hb * PDIM;
        const int b0 = 2 * hb;
        const float* r0 = x + (size_t)b0 * (A_ * PP) + (size_t)i1 * PDIM;
        const float* r1 = r0 + (size_t)(A_ * PP);
        for (int e = t; e < A_ * ROWW; e += BLK) {
            int j = e / ROWW;
            int p = e - j * ROWW;
            int k = p - PADL;
            float f0 = 0.0f, f1 = 0.0f;
            if (k >= 0 && k < PDIM) {
                size_t o = (size_t)j * PP + k;
                f0 = r0[o];
                f1 = r1[o];
            }
            dr[e] = __builtin_bit_cast(unsigned int,
                        __halves2half2(__float2half_rn(f0), __float2half_rn(f1)));
        }
        __syncthreads();

        float a0[NV] = {0.0f, 0.0f, 0.0f};
        float a1[NV] = {0.0f, 0.0f, 0.0f};
#pragma unroll 2
        for (int j = 0; j < A_; ++j) {
            float2 cj = cs_lds[j];
            const unsigned int* base = &dr[j * ROWW];
#pragma unroll
            for (int nn = 0; nn < NV; ++nn) {
                float ixp = fmaf(u2[nn], cj.x, fmaf(u0[nn], cj.y, 23.0f));
                int   kp  = (int)ixp;
                float w1  = FRACTF(ixp);
                unsigned int wp = __builtin_bit_cast(unsigned int,
                                    __builtin_amdgcn_cvt_pkrtz(1.0f - w1, w1));
                unsigned int d0 = base[kp];
                unsigned int d1 = base[kp + 1];
                unsigned int p0 = __builtin_amdgcn_perm(d1, d0, 0x05040100u);
                unsigned int p1 = __builtin_amdgcn_perm(d1, d0, 0x07060302u);
                a0[nn] = fdot2u(p0, wp, a0[nn]);
                a1[nn] = fdot2u(p1, wp, a1[nn]);
            }
        }

        float* ob0 = out + (size_t)b0 * OUTB + (size_t)i1 * PDIM;
        float* ob1 = ob0 + (size_t)OUTB;
#pragma unroll
        for (int nn = 0; nn < NV; ++nn) {
            int n = t + nn * BLK;
            if (n < PP) {
                int q0 = n / PDIM;
                int q2 = n - q0 * PDIM;
                size_t o = (size_t)q0 * PP + q2;
                ob0[o] = a0[nn] * invA;
                ob1[o] = a1[nn] * invA;
            }
        }
    }
}

// ---------------- launch ----------------

extern "C" void kernel_launch(void* const* d_in, const int* in_sizes, int n_in,
                              void* d_out, int out_size, void* d_ws, size_t ws_size,
                              hipStream_t stream)
{
    const float* x      = (const float*)d_in[0];
    const float* angles = (const float*)d_in[1];
    float* out          = (float*)d_out;

    const int A = in_sizes[1];                    // 121
    const int B = in_sizes[0] / (A * PP);         // 128
    const float invA = 1.0f / (float)A;

    const size_t wBytes  = (size_t)MP * KP * sizeof(__half);         // 9.29 MB
    const size_t xtBytes = (size_t)(PDIM * B) * KP * sizeof(__half); // 34.1 MB

    if (ws_size >= wBytes + xtBytes && A == A_ && B == 128) {
        __half* W  = (__half*)d_ws;
        __half* Xt = (__half*)((char*)d_ws + wBytes);
        prep_kernel<<<PDIM * B + MP, 256, 0, stream>>>(x, angles, Xt, W);
        gemm_kernel<<<NWG, 256, 0, stream>>>(W, Xt, out, invA);
    } else {
        const int nslice = (B / 2) * PDIM;
        dim3 grid(GRID < nslice ? GRID : nslice);
        fbp_adjoint_kernel<<<grid, BLK, 0, stream>>>(x, angles, out,
                                                     nslice, invA);
    }
}